// Round 3
// baseline (651.793 us; speedup 1.0000x reference)
//
#include <hip/hip_runtime.h>
#include <math.h>

typedef unsigned short u16;
typedef unsigned int u32;
typedef __attribute__((ext_vector_type(8))) short short8;   // 8 bf16 (4 VGPRs)
typedef __attribute__((ext_vector_type(4))) float f32x4;

__device__ __forceinline__ float bf2f(u16 u) {
  union { u32 i; float f; } v; v.i = ((u32)u) << 16; return v.f;
}
__device__ __forceinline__ u16 f2bf(float f) {
  union { float f; u32 i; } v; v.f = f;
  u32 i = v.i;
  i += 0x7fffu + ((i >> 16) & 1u);   // round-to-nearest-even
  return (u16)(i >> 16);
}

// dtype-polymorphic loads (F32: inputs are float32; else bf16 bits)
template<bool F32>
__device__ __forceinline__ float ld(const void* p, int i) {
  if (F32) return ((const float*)p)[i];
  return bf2f(((const u16*)p)[i]);
}

// ---------------------------------------------------------------------------
// Workspace layout (bytes). Total 107,584 B. All offsets 16-aligned.
// ---------------------------------------------------------------------------
#define WS_FLAG   0
#define WS_QKVF   64        // short8[1536]:  [w][nt3][kt2][lane]  (24576 B)
#define WS_PROJF  24640     // short8[512]:   [w][kt2][lane]       ( 8192 B)
#define WS_B1F    32832     // short8[2048]:  [w][kt2][nt4][lane]  (32768 B)
#define WS_B2F    65600     // short8[2048]:  [w][kt8][lane]       (32768 B)
#define WS_QB     98368     // f32[768]:      [w][nt3][lane]       ( 3072 B)
#define WS_PB     101440    // f32[256]:      [w][lane]            ( 1024 B)
#define WS_B1V    102464    // f32[1024]:     [w][nt4][lane]       ( 4096 B)
#define WS_B2V    106560    // f32[256]:      [w][lane]            ( 1024 B)

// ---------------------------------------------------------------------------
// Kernel 0: detect input dtype (fp32 vs bf16-packed).
// ---------------------------------------------------------------------------
__global__ __launch_bounds__(64)
void detect_kernel(const void* __restrict__ xv, int* __restrict__ flag) {
  const u32* xw = (const u32*)xv;
  const int t = threadIdx.x;
  int bad = 0;
  for (int i = t; i < 1024; i += 64) {
    const int e = (int)((xw[i] >> 7) & 0xFF);
    if (e < 90 || e > 150) bad++;
  }
#pragma unroll
  for (int m = 1; m < 64; m <<= 1) bad += __shfl_xor(bad, m);
  if (t == 0) *flag = (bad > 256) ? 1 : 0;
}

// ---------------------------------------------------------------------------
// Kernel 0.5: pack all weight fragments (bf16, MFMA B-layout) + biases into ws.
// B layout (verified): n = lane&15, k = quad*8 + j, k split as kt*32 + quad*8+j.
// ---------------------------------------------------------------------------
template<bool F32>
__device__ void pack_body(const void* __restrict__ qkvw, const void* __restrict__ qkvb,
                          const void* __restrict__ projw, const void* __restrict__ projb,
                          const void* __restrict__ mw1, const void* __restrict__ mb1,
                          const void* __restrict__ mw2, const void* __restrict__ mb2,
                          char* __restrict__ ws)
{
  const int g  = blockIdx.x * 256 + threadIdx.x;
  const int gs = gridDim.x * 256;
  u16*  qkvF = (u16*)(ws + WS_QKVF);
  u16*  projF = (u16*)(ws + WS_PROJF);
  u16*  b1fF = (u16*)(ws + WS_B1F);
  u16*  b2fF = (u16*)(ws + WS_B2F);
  float* qbA = (float*)(ws + WS_QB);
  float* pbA = (float*)(ws + WS_PB);
  float* b1vA = (float*)(ws + WS_B1V);
  float* b2vA = (float*)(ws + WS_B2V);

  for (int e = g; e < 1536; e += gs) {                 // qkv frags
    const int w = e / 384, m = (e >> 6) % 6, nt = m >> 1, kt = m & 1, l = e & 63;
    const int quad = l >> 4, col = l & 15;
#pragma unroll
    for (int j = 0; j < 8; ++j)
      qkvF[e*8 + j] = f2bf(ld<F32>(qkvw, (kt*32 + quad*8 + j)*192 + w*48 + nt*16 + col));
  }
  for (int e = g; e < 512; e += gs) {                  // proj frags
    const int w = e >> 7, kt = (e >> 6) & 1, l = e & 63;
    const int quad = l >> 4, col = l & 15;
#pragma unroll
    for (int j = 0; j < 8; ++j)
      projF[e*8 + j] = f2bf(ld<F32>(projw, (kt*32 + quad*8 + j)*64 + w*16 + col));
  }
  for (int e = g; e < 2048; e += gs) {                 // W1 frags [w][kt][nt]
    const int w = e >> 9, km = (e >> 6) & 7, kt = km >> 2, nt = km & 3, l = e & 63;
    const int quad = l >> 4, col = l & 15;
#pragma unroll
    for (int j = 0; j < 8; ++j)
      b1fF[e*8 + j] = f2bf(ld<F32>(mw1, (kt*32 + quad*8 + j)*256 + w*64 + nt*16 + col));
  }
  for (int e = g; e < 2048; e += gs) {                 // W2 frags [w][kt]
    const int w = e >> 9, kt = (e >> 6) & 7, l = e & 63;
    const int quad = l >> 4, col = l & 15;
#pragma unroll
    for (int j = 0; j < 8; ++j)
      b2fF[e*8 + j] = f2bf(ld<F32>(mw2, (kt*32 + quad*8 + j)*64 + w*16 + col));
  }
  for (int e = g; e < 768; e += gs) {                  // qkv bias
    const int w = e / 192, nt = (e >> 6) % 3;
    qbA[e] = ld<F32>(qkvb, w*48 + nt*16 + (e & 15));
  }
  for (int e = g; e < 256; e += gs)                    // proj bias
    pbA[e] = ld<F32>(projb, (e >> 6)*16 + (e & 15));
  for (int e = g; e < 1024; e += gs) {                 // mlp b1
    const int w = e >> 8, nt = (e >> 6) & 3;
    b1vA[e] = ld<F32>(mb1, w*64 + nt*16 + (e & 15));
  }
  for (int e = g; e < 256; e += gs)                    // mlp b2
    b2vA[e] = ld<F32>(mb2, (e >> 6)*16 + (e & 15));
}

__global__ __launch_bounds__(256)
void pack_kernel(const void* qkvw, const void* qkvb, const void* projw, const void* projb,
                 const void* mw1, const void* mb1, const void* mw2, const void* mb2,
                 char* ws)
{
  if (*(const int*)ws) pack_body<true >(qkvw, qkvb, projw, projb, mw1, mb1, mw2, mb2, ws);
  else                 pack_body<false>(qkvw, qkvb, projw, projb, mw1, mb1, mw2, mb2, ws);
}

// ---------------------------------------------------------------------------
// Helpers: shifted-gather prefetch and bug-faithful scatter address.
// ---------------------------------------------------------------------------
template<bool F32>
__device__ __forceinline__ void gather_pf(const void* __restrict__ x, int chunk,
                                          int w, int l, float* pf) {
  const int b = chunk >> 13;
  const int wbase = (chunk & 8191) << 2;
  const int widx = wbase + w;
  const int wz = widx >> 10, wy = (widx >> 5) & 31, wx = widx & 31;
#pragma unroll
  for (int t = 0; t < 8; ++t) {
    const int od = (2*wz + ((t>>2)&1) + 1) & 63;
    const int oh = (2*wy + ((t>>1)&1) + 1) & 63;
    const int ow = (2*wx + ( t    &1) + 1) & 63;
    pf[t] = ld<F32>(x, (((b<<18) + ((od<<12)|(oh<<6)|ow)) << 6) + l);
  }
}

__device__ __forceinline__ int scat(int wbase, int b, int tok) {
  const int widx = wbase + (tok >> 3);
  const int s    = tok & 7;
  const int wz = widx >> 10, wy = (widx >> 5) & 31, wx = widx & 31;
  const int fd = (2*wz + ((wy>>3)&1) + 1) & 63;
  const int Hb = 8*(wy&7) + 4*(wx>>4) + (wy>>4);
  const int Wb = 4*(wx&15);
  const int i = (s>>2)&1, j = (s>>1)&1, k = s&1;
  const int fh = (Hb + 2*j + 1) & 63;
  const int fw = (Wb + 2*i + k + 1) & 63;
  return ((b<<18) + ((fd<<12)|(fh<<6)|fw)) << 6;
}

// ---------------------------------------------------------------------------
// Fused kernel: LN1 + window-attn + proj + residual + LN2 + MLP + residual.
// Block = 256 thr (4 waves), chunk = 4 windows = 32 tokens, 16384 chunks,
// persistent grid 2048 (8 chunks/block). Weight frags streamed from ws
// (keeps VGPR ~<112 -> 4 waves/SIMD). LDS pool 30.2 KB with overlays:
//   aL  [0,2304)     LN1 out -> LN2 out
//   qL  [2304,4608)  q -> attention O
//   kL  [4608,6912)  k     \  overlaid by hL[32][264] = [2304,10752)
//   vL  [6912,9216)  v     /  (k/v dead after softmax, q dead after proj)
//   yL  [10752,15104) fp32[32][68]: y = x + attn + pb
// 6 barriers/chunk. Gather loads software-pipelined across chunks.
// ---------------------------------------------------------------------------
#define MFMA __builtin_amdgcn_mfma_f32_16x16x32_bf16

template<bool F32>
__device__ __forceinline__ void fused_body(
    const void* __restrict__ x,
    const void* __restrict__ n1g, const void* __restrict__ n1b,
    const void* __restrict__ rpb,
    const void* __restrict__ n2g, const void* __restrict__ n2b,
    const char* __restrict__ ws,
    float* __restrict__ out,
    u16* __restrict__ P)
{
  u16* aL = P;
  u16* qL = P + 2304;
  u16* kL = P + 4608;
  u16* vL = P + 6912;
  u16* hL = P + 2304;                    // overlay (see header comment)
  float* yL = (float*)(P + 10752);

  const int tid = threadIdx.x;
  const int w = tid >> 6, l = tid & 63;
  const int quad = l >> 4, col = l & 15;
  const int hh = l >> 3, qi = l & 7;

  const short8* qkvF  = (const short8*)(ws + WS_QKVF);
  const short8* projF = (const short8*)(ws + WS_PROJF);
  const short8* b1fF  = (const short8*)(ws + WS_B1F);
  const short8* b2fF  = (const short8*)(ws + WS_B2F);
  const float*  qbA   = (const float*)(ws + WS_QB);
  const float*  pbA   = (const float*)(ws + WS_PB);
  const float*  b1vA  = (const float*)(ws + WS_B1V);
  const float*  b2vA  = (const float*)(ws + WS_B2V);

  const float g1 = ld<F32>(n1g, l), be1 = ld<F32>(n1b, l);
  const float g2 = ld<F32>(n2g, l), be2 = ld<F32>(n2b, l);
  float qb[3];
#pragma unroll
  for (int nt = 0; nt < 3; ++nt) qb[nt] = qbA[(w*3 + nt)*64 + l];
  const float pbv = pbA[w*64 + l];
  float b1v[4];
#pragma unroll
  for (int nt = 0; nt < 4; ++nt) b1v[nt] = b1vA[(w*4 + nt)*64 + l];
  const float b2v = b2vA[w*64 + l];
  const int rel = 3 * (((hh>>1)&1) - ((qi>>1)&1) + 1)
                +     (((hh>>2)&1) - ((qi>>2)&1) + 1)
                +     (( hh    &1) - ( qi    &1) + 1);
  float rpv[8];
#pragma unroll
  for (int kk = 0; kk < 8; ++kk) rpv[kk] = ld<F32>(rpb, rel*8 + kk);

  float pf[8];
  gather_pf<F32>(x, blockIdx.x, w, l, pf);      // prologue prefetch

  for (int chunk = blockIdx.x; chunk < 16384; chunk += 2048) {
    const int b     = chunk >> 13;
    const int wbase = (chunk & 8191) << 2;
    const int widx0 = wbase + w;
    const int wz0 = widx0 >> 10, wy0 = (widx0 >> 5) & 31, wx0 = widx0 & 31;

    // ---- phase 1: LN1 on prefetched gather (lane = channel) ----
#pragma unroll
    for (int t = 0; t < 8; ++t) {
      const float v = pf[t];
      float s1 = v, sq = v * v;
#pragma unroll
      for (int m = 1; m < 64; m <<= 1) {
        s1 += __shfl_xor(s1, m);
        sq += __shfl_xor(sq, m);
      }
      const float mu  = s1 * 0.015625f;
      const float var = sq * 0.015625f - mu * mu;
      aL[(w*8 + t)*72 + l] = f2bf((v - mu) * rsqrtf(var + 1e-5f) * g1 + be1);
    }
    if (chunk + 2048 < 16384) gather_pf<F32>(x, chunk + 2048, w, l, pf);
    __syncthreads();                                       // B1: aL ready

    // ---- phase 2: QKV MFMA (streamed B-frags), wave's 48 cols ----
    {
      short8 aF[2][2];
#pragma unroll
      for (int mt = 0; mt < 2; ++mt)
#pragma unroll
        for (int kt = 0; kt < 2; ++kt)
          aF[mt][kt] = *(const short8*)&aL[(mt*16 + col)*72 + kt*32 + quad*8];
#pragma unroll
      for (int nt = 0; nt < 3; ++nt) {
        const short8 f0 = qkvF[(w*6 + nt*2 + 0)*64 + l];
        const short8 f1 = qkvF[(w*6 + nt*2 + 1)*64 + l];
        f32x4 a0 = (f32x4){0.f,0.f,0.f,0.f}, a1 = (f32x4){0.f,0.f,0.f,0.f};
        a0 = MFMA(aF[0][0], f0, a0, 0, 0, 0);
        a0 = MFMA(aF[0][1], f1, a0, 0, 0, 0);
        a1 = MFMA(aF[1][0], f0, a1, 0, 0, 0);
        a1 = MFMA(aF[1][1], f1, a1, 0, 0, 0);
        const int nb  = w*48 + nt*16;
        u16* dst      = (nb < 64) ? qL : (nb < 128) ? kL : vL;
        const int chb = (nb & 63) + col;
        const float scl = (nb < 64) ? 0.35355339059327373f : 1.0f;
        const float bb  = qb[nt];
#pragma unroll
        for (int r = 0; r < 4; ++r) {
          dst[(quad*4 + r)*72 + chb]        = f2bf((a0[r] + bb) * scl);
          dst[(16 + quad*4 + r)*72 + chb]   = f2bf((a1[r] + bb) * scl);
        }
      }
    }
    __syncthreads();                                       // B2: q/k/v ready

    // ---- phase 3: per-(window,head) softmax; wave w -> window w ----
    {
      const int tq = w*8 + qi;
      float qr[8];
      {
        const short8 qv = *(const short8*)&qL[tq*72 + hh*8];
#pragma unroll
        for (int d = 0; d < 8; ++d) qr[d] = bf2f((u16)qv[d]);
      }
      float sc8[8];
#pragma unroll
      for (int kk = 0; kk < 8; ++kk) {
        const short8 kv = *(const short8*)&kL[(w*8 + kk)*72 + hh*8];
        float a = 0.f;
#pragma unroll
        for (int d = 0; d < 8; ++d) a += qr[d] * bf2f((u16)kv[d]);
        sc8[kk] = a + rpv[kk];
      }
      {
        int cnts[8];
#pragma unroll
        for (int p = 0; p < 8; ++p) {
          const int sd = 2*wz0 + ((p>>2)&1);
          const int sh = 2*wy0 + ((p>>1)&1);
          const int sw = 2*wx0 + (p&1);
          cnts[p] = (sd >= 62 ? sd - 61 : 0)*9 + (sh >= 62 ? sh - 61 : 0)*3
                  + (sw >= 62 ? sw - 61 : 0);
        }
#pragma unroll
        for (int kk = 0; kk < 8; ++kk)
          if (cnts[kk] != cnts[qi]) sc8[kk] -= 100.f;
      }
      float mx = sc8[0];
#pragma unroll
      for (int kk = 1; kk < 8; ++kk) mx = fmaxf(mx, sc8[kk]);
      float pr[8], lsum = 0.f;
#pragma unroll
      for (int kk = 0; kk < 8; ++kk) { pr[kk] = __expf(sc8[kk] - mx); lsum += pr[kk]; }
      const float inv = __builtin_amdgcn_rcpf(lsum);
      float o[8];
#pragma unroll
      for (int d = 0; d < 8; ++d) o[d] = 0.f;
#pragma unroll
      for (int kk = 0; kk < 8; ++kk) {
        const short8 vv = *(const short8*)&vL[(w*8 + kk)*72 + hh*8];
#pragma unroll
        for (int d = 0; d < 8; ++d) o[d] += pr[kk] * bf2f((u16)vv[d]);
      }
      short8 ov;
#pragma unroll
      for (int d = 0; d < 8; ++d) ov[d] = (short)f2bf(o[d] * inv);
      *(short8*)&qL[tq*72 + hh*8] = ov;   // O into own q-slot (lane-private)
    }
    // prefetch residual x + scatter offsets (consumed phase 4 / final store)
    int offs[8]; float xr[8];
#pragma unroll
    for (int mt = 0; mt < 2; ++mt)
#pragma unroll
      for (int r = 0; r < 4; ++r) {
        const int off = scat(wbase, b, mt*16 + quad*4 + r) + w*16 + col;
        offs[mt*4 + r] = off;
        xr[mt*4 + r] = ld<F32>(x, off);
      }
    __syncthreads();                                       // B3: O ready

    // ---- phase 4: proj MFMA + y -> yL (fp32) ----
    {
      const short8 p0 = projF[(w*2 + 0)*64 + l];
      const short8 p1 = projF[(w*2 + 1)*64 + l];
      f32x4 c0 = (f32x4){0.f,0.f,0.f,0.f}, c1 = (f32x4){0.f,0.f,0.f,0.f};
      c0 = MFMA(*(const short8*)&qL[(col)*72 + quad*8],         p0, c0, 0, 0, 0);
      c0 = MFMA(*(const short8*)&qL[(col)*72 + 32 + quad*8],    p1, c0, 0, 0, 0);
      c1 = MFMA(*(const short8*)&qL[(16+col)*72 + quad*8],      p0, c1, 0, 0, 0);
      c1 = MFMA(*(const short8*)&qL[(16+col)*72 + 32 + quad*8], p1, c1, 0, 0, 0);
#pragma unroll
      for (int r = 0; r < 4; ++r) {
        yL[(quad*4 + r)*68 + w*16 + col]      = xr[r]     + c0[r] + pbv;
        yL[(16 + quad*4 + r)*68 + w*16 + col] = xr[4 + r] + c1[r] + pbv;
      }
    }
    __syncthreads();                                       // B4: yL ready

    // ---- phase 5: LN2 (lane = channel) -> aL (reused) ----
#pragma unroll
    for (int t = 0; t < 8; ++t) {
      const float v = yL[(w*8 + t)*68 + l];
      float s1 = v, sq = v * v;
#pragma unroll
      for (int m = 1; m < 64; m <<= 1) {
        s1 += __shfl_xor(s1, m);
        sq += __shfl_xor(sq, m);
      }
      const float mu  = s1 * 0.015625f;
      const float var = sq * 0.015625f - mu * mu;
      aL[(w*8 + t)*72 + l] = f2bf((v - mu) * rsqrtf(var + 1e-5f) * g2 + be2);
    }
    __syncthreads();                                       // B5: aL2 ready

    // ---- phase 6: MLP GEMM1 (streamed W1 frags) + tanh-GELU -> hL ----
    {
      short8 aF[2][2];
#pragma unroll
      for (int mt = 0; mt < 2; ++mt)
#pragma unroll
        for (int kt = 0; kt < 2; ++kt)
          aF[mt][kt] = *(const short8*)&aL[(mt*16 + col)*72 + kt*32 + quad*8];
#pragma unroll
      for (int nt = 0; nt < 4; ++nt) {
        const short8 g0f = b1fF[(w*8 + 0 + nt)*64 + l];
        const short8 g1f = b1fF[(w*8 + 4 + nt)*64 + l];
        f32x4 m0 = (f32x4){0.f,0.f,0.f,0.f}, m1 = (f32x4){0.f,0.f,0.f,0.f};
        m0 = MFMA(aF[0][0], g0f, m0, 0, 0, 0);
        m0 = MFMA(aF[0][1], g1f, m0, 0, 0, 0);
        m1 = MFMA(aF[1][0], g0f, m1, 0, 0, 0);
        m1 = MFMA(aF[1][1], g1f, m1, 0, 0, 0);
        const float bb = b1v[nt];
#pragma unroll
        for (int r = 0; r < 4; ++r) {
          {
            const float h = m0[r] + bb;
            const float u = h * (1.5957691216f + 0.0713548162f * (h * h));
            const float e = __expf(u);
            hL[(quad*4 + r)*264 + w*64 + nt*16 + col] =
                f2bf(h - h * __builtin_amdgcn_rcpf(e + 1.f));
          }
          {
            const float h = m1[r] + bb;
            const float u = h * (1.5957691216f + 0.0713548162f * (h * h));
            const float e = __expf(u);
            hL[(16 + quad*4 + r)*264 + w*64 + nt*16 + col] =
                f2bf(h - h * __builtin_amdgcn_rcpf(e + 1.f));
          }
        }
      }
    }
    __syncthreads();                                       // B6: hL ready

    // ---- phase 7: MLP GEMM2 (streamed W2 frags) + final scattered store ----
    {
      f32x4 o0 = (f32x4){0.f,0.f,0.f,0.f}, o1 = (f32x4){0.f,0.f,0.f,0.f};
#pragma unroll
      for (int kt = 0; kt < 8; ++kt) {
        const short8 bf = b2fF[(w*8 + kt)*64 + l];
        o0 = MFMA(*(const short8*)&hL[(col)*264 + kt*32 + quad*8],    bf, o0, 0, 0, 0);
        o1 = MFMA(*(const short8*)&hL[(16+col)*264 + kt*32 + quad*8], bf, o1, 0, 0, 0);
      }
#pragma unroll
      for (int r = 0; r < 4; ++r) {
        out[offs[r]]     = yL[(quad*4 + r)*68 + w*16 + col]      + o0[r] + b2v;
        out[offs[4 + r]] = yL[(16 + quad*4 + r)*68 + w*16 + col] + o1[r] + b2v;
      }
    }
    // No trailing barrier: next phase-1 writes only aL (disjoint from hL/yL
    // reads above); B1 fences before next q/k/v writes into the hL region.
  }
}

__global__ __launch_bounds__(256, 4)
void fused_kernel(const void* __restrict__ x,
                  const void* __restrict__ n1g, const void* __restrict__ n1b,
                  const void* __restrict__ rpb,
                  const void* __restrict__ n2g, const void* __restrict__ n2b,
                  const char* __restrict__ ws, float* __restrict__ out)
{
  __shared__ __align__(16) u16 P[15104];   // 30,208 B pool (see fused_body)
  if (*(const int*)ws)
    fused_body<true >(x, n1g, n1b, rpb, n2g, n2b, ws, out, P);
  else
    fused_body<false>(x, n1g, n1b, rpb, n2g, n2b, ws, out, P);
}

extern "C" void kernel_launch(void* const* d_in, const int* in_sizes, int n_in,
                              void* d_out, int out_size, void* d_ws, size_t ws_size,
                              hipStream_t stream) {
  const void* x     = d_in[0];
  const void* n1g   = d_in[1];
  const void* n1b   = d_in[2];
  const void* qkvw  = d_in[3];
  const void* qkvb  = d_in[4];
  const void* rpb   = d_in[5];
  const void* projw = d_in[6];
  const void* projb = d_in[7];
  const void* n2g   = d_in[8];
  const void* n2b   = d_in[9];
  const void* mw1   = d_in[10];
  const void* mb1   = d_in[11];
  const void* mw2   = d_in[12];
  const void* mb2   = d_in[13];
  float* out = (float*)d_out;
  char* ws   = (char*)d_ws;     // needs ~108 KB of workspace
  (void)ws_size;

  detect_kernel<<<dim3(1), dim3(64), 0, stream>>>(x, (int*)ws);
  pack_kernel<<<dim3(8), dim3(256), 0, stream>>>(
      qkvw, qkvb, projw, projb, mw1, mb1, mw2, mb2, ws);
  fused_kernel<<<dim3(2048), dim3(256), 0, stream>>>(
      x, n1g, n1b, rpb, n2g, n2b, ws, out);
}

// Round 4
// 445.801 us; speedup vs baseline: 1.4621x; 1.4621x over previous
//
#include <hip/hip_runtime.h>
#include <math.h>

typedef unsigned short u16;
typedef unsigned int u32;
typedef __attribute__((ext_vector_type(8))) short short8;   // 8 bf16 (4 VGPRs)
typedef __attribute__((ext_vector_type(4))) float f32x4;

__device__ __forceinline__ float bf2f(u16 u) {
  union { u32 i; float f; } v; v.i = ((u32)u) << 16; return v.f;
}
__device__ __forceinline__ u16 f2bf(float f) {
  union { float f; u32 i; } v; v.f = f;
  u32 i = v.i;
  i += 0x7fffu + ((i >> 16) & 1u);   // round-to-nearest-even
  return (u16)(i >> 16);
}

// dtype-polymorphic loads (F32: inputs are float32; else bf16 bits)
template<bool F32>
__device__ __forceinline__ float ld(const void* p, int i) {
  if (F32) return ((const float*)p)[i];
  return bf2f(((const u16*)p)[i]);
}

// ---------------------------------------------------------------------------
// Kernel 0: detect input dtype (fp32 vs bf16-packed).
// ---------------------------------------------------------------------------
__global__ __launch_bounds__(64)
void detect_kernel(const void* __restrict__ xv, int* __restrict__ flag) {
  const u32* xw = (const u32*)xv;
  const int t = threadIdx.x;
  int bad = 0;
  for (int i = t; i < 1024; i += 64) {
    const int e = (int)((xw[i] >> 7) & 0xFF);
    if (e < 90 || e > 150) bad++;
  }
#pragma unroll
  for (int m = 1; m < 64; m <<= 1) bad += __shfl_xor(bad, m);
  if (t == 0) *flag = (bad > 256) ? 1 : 0;
}

// ---------------------------------------------------------------------------
// Token-major shifted gather: lane (s, cg) loads token s's channels cg*8..+7
// of window (wbase + w) as two dwordx4 (coalesced: 8 lanes cover a 256B row).
// ---------------------------------------------------------------------------
template<bool F32>
__device__ __forceinline__ void gather8(const void* __restrict__ x, int chunk,
                                        int w, int s, int cg, float* pf) {
  const int b     = chunk >> 13;
  const int wbase = (chunk & 8191) << 2;
  const int widx  = wbase + w;
  const int wz = widx >> 10, wy = (widx >> 5) & 31, wx = widx & 31;
  const int od = (2*wz + ((s>>2)&1) + 1) & 63;
  const int oh = (2*wy + ((s>>1)&1) + 1) & 63;
  const int ow = (2*wx + ( s    &1) + 1) & 63;
  const int base = (((b<<18) + ((od<<12)|(oh<<6)|ow)) << 6) + cg*8;
  if (F32) {
    const f32x4 a = *(const f32x4*)((const float*)x + base);
    const f32x4 c = *(const f32x4*)((const float*)x + base + 4);
    pf[0]=a[0]; pf[1]=a[1]; pf[2]=a[2]; pf[3]=a[3];
    pf[4]=c[0]; pf[5]=c[1]; pf[6]=c[2]; pf[7]=c[3];
  } else {
    const short8 a = *(const short8*)((const u16*)x + base);
#pragma unroll
    for (int j = 0; j < 8; ++j) pf[j] = bf2f((u16)a[j]);
  }
}

// bug-faithful window-reverse scatter base for token tok of chunk's windows
__device__ __forceinline__ int scat(int wbase, int b, int tok) {
  const int widx = wbase + (tok >> 3);
  const int s    = tok & 7;
  const int wz = widx >> 10, wy = (widx >> 5) & 31, wx = widx & 31;
  const int fd = (2*wz + ((wy>>3)&1) + 1) & 63;
  const int Hb = 8*(wy&7) + 4*(wx>>4) + (wy>>4);
  const int Wb = 4*(wx&15);
  const int i = (s>>2)&1, j = (s>>1)&1, k = s&1;
  const int fh = (Hb + 2*j + 1) & 63;
  const int fw = (Wb + 2*i + k + 1) & 63;
  return ((b<<18) + ((fd<<12)|(fh<<6)|fw)) << 6;
}

// ---------------------------------------------------------------------------
// Kernel 1: LN1 + shifted-window attention + proj + residual -> out (y, fp32).
// Block 256 thr (4 waves), chunk = 4 windows = 32 tokens, persistent grid 2048.
// Weight fragments register-resident (the round-3 streaming regression showed
// per-chunk weight reloads thrash L2). LN1 = token-major 3-stage group reduce.
// ---------------------------------------------------------------------------
#define MFMA __builtin_amdgcn_mfma_f32_16x16x32_bf16

template<bool F32>
__device__ __forceinline__ void attn_body(
    const void* __restrict__ x,
    const void* __restrict__ n1g, const void* __restrict__ n1b,
    const void* __restrict__ qkvw, const void* __restrict__ qkvb,
    const void* __restrict__ rpb,
    const void* __restrict__ projw, const void* __restrict__ projb,
    float* __restrict__ out,
    u16* __restrict__ aL, u16* __restrict__ qL,
    u16* __restrict__ kL, u16* __restrict__ vL)
{
  const int tid  = threadIdx.x;
  const int w    = tid >> 6, l = tid & 63;
  const int quad = l >> 4,  col = l & 15;
  const int s8   = l >> 3,  cg  = l & 7;   // token-major split (= hh, qi)

  // LN1 per-channel params for this lane's 8 channels
  float g1v[8], be1v[8];
#pragma unroll
  for (int j = 0; j < 8; ++j) {
    g1v[j]  = ld<F32>(n1g, cg*8 + j);
    be1v[j] = ld<F32>(n1b, cg*8 + j);
  }

  // ---- register-resident weight fragments (once per block) ----
  short8 bq[3][2];                 // qkv cols w*48 + nt*16 + col, [nt][kt]
#pragma unroll
  for (int nt = 0; nt < 3; ++nt)
#pragma unroll
    for (int kt = 0; kt < 2; ++kt) {
      short8 f;
#pragma unroll
      for (int j = 0; j < 8; ++j)
        f[j] = (short)f2bf(ld<F32>(qkvw, (kt*32 + quad*8 + j)*192 + w*48 + nt*16 + col));
      bq[nt][kt] = f;
    }
  float qb[3];
#pragma unroll
  for (int nt = 0; nt < 3; ++nt) qb[nt] = ld<F32>(qkvb, w*48 + nt*16 + col);
  short8 bp[2];                    // proj cols w*16 + col, [kt]
#pragma unroll
  for (int kt = 0; kt < 2; ++kt) {
    short8 f;
#pragma unroll
    for (int j = 0; j < 8; ++j)
      f[j] = (short)f2bf(ld<F32>(projw, (kt*32 + quad*8 + j)*64 + w*16 + col));
    bp[kt] = f;
  }
  const float pbv = ld<F32>(projb, w*16 + col);
  const int rel = 3 * (((s8>>1)&1) - ((cg>>1)&1) + 1)
                +     (((s8>>2)&1) - ((cg>>2)&1) + 1)
                +     (( s8    &1) - ( cg    &1) + 1);

  float pf[8];
  gather8<F32>(x, blockIdx.x, w, s8, cg, pf);   // prologue prefetch

  for (int chunk = blockIdx.x; chunk < 16384; chunk += 2048) {
    const int b     = chunk >> 13;
    const int wbase = (chunk & 8191) << 2;
    const int widx0 = wbase + w;
    const int wz0 = widx0 >> 10, wy0 = (widx0 >> 5) & 31, wx0 = widx0 & 31;

    // ---- phase 1: LN1, token-major 8-lane-group reduce ----
    {
      float s1 = 0.f, sq = 0.f;
#pragma unroll
      for (int j = 0; j < 8; ++j) { s1 += pf[j]; sq += pf[j]*pf[j]; }
#pragma unroll
      for (int m = 1; m < 8; m <<= 1) {
        s1 += __shfl_xor(s1, m);
        sq += __shfl_xor(sq, m);
      }
      const float mu  = s1 * 0.015625f;
      const float var = sq * 0.015625f - mu * mu;
      const float rs  = rsqrtf(var + 1e-5f);
      short8 av;
#pragma unroll
      for (int j = 0; j < 8; ++j)
        av[j] = (short)f2bf((pf[j] - mu) * rs * g1v[j] + be1v[j]);
      *(short8*)&aL[(w*8 + s8)*72 + cg*8] = av;
    }
    if (chunk + 2048 < 16384) gather8<F32>(x, chunk + 2048, w, s8, cg, pf);
    __syncthreads();                                       // B1: aL ready

    // ---- phase 2: QKV MFMA, A[32x64] @ wave's 64x48 slab -> q/k/v LDS ----
    {
      short8 aF[2][2];
#pragma unroll
      for (int mt = 0; mt < 2; ++mt)
#pragma unroll
        for (int kt = 0; kt < 2; ++kt)
          aF[mt][kt] = *(const short8*)&aL[(mt*16 + col)*72 + kt*32 + quad*8];
#pragma unroll
      for (int nt = 0; nt < 3; ++nt) {
        f32x4 a0 = (f32x4){0.f,0.f,0.f,0.f}, a1 = (f32x4){0.f,0.f,0.f,0.f};
        a0 = MFMA(aF[0][0], bq[nt][0], a0, 0, 0, 0);
        a0 = MFMA(aF[0][1], bq[nt][1], a0, 0, 0, 0);
        a1 = MFMA(aF[1][0], bq[nt][0], a1, 0, 0, 0);
        a1 = MFMA(aF[1][1], bq[nt][1], a1, 0, 0, 0);
        const int nb  = w*48 + nt*16;
        u16* dst      = (nb < 64) ? qL : (nb < 128) ? kL : vL;
        const int chb = (nb & 63) + col;
        const float scl = (nb < 64) ? 0.35355339059327373f : 1.0f;
        const float bb  = qb[nt];
#pragma unroll
        for (int r = 0; r < 4; ++r) {
          dst[(quad*4 + r)*72 + chb]      = f2bf((a0[r] + bb) * scl);
          dst[(16 + quad*4 + r)*72 + chb] = f2bf((a1[r] + bb) * scl);
        }
      }
    }
    __syncthreads();                                       // B2: q/k/v ready

    // ---- phase 3: softmax for window w (lane = (head s8, query cg)) ----
    {
      const int tq = w*8 + cg;
      float qr[8];
      {
        const short8 qv = *(const short8*)&qL[tq*72 + s8*8];
#pragma unroll
        for (int d = 0; d < 8; ++d) qr[d] = bf2f((u16)qv[d]);
      }
      float sc8[8];
#pragma unroll
      for (int kk = 0; kk < 8; ++kk) {
        const short8 kv = *(const short8*)&kL[(w*8 + kk)*72 + s8*8];
        float a = 0.f;
#pragma unroll
        for (int d = 0; d < 8; ++d) a += qr[d] * bf2f((u16)kv[d]);
        sc8[kk] = a + ld<F32>(rpb, rel*8 + kk);
      }
      {
        int cnts[8];
#pragma unroll
        for (int p = 0; p < 8; ++p) {
          const int sd = 2*wz0 + ((p>>2)&1);
          const int sh = 2*wy0 + ((p>>1)&1);
          const int sw = 2*wx0 + (p&1);
          cnts[p] = (sd >= 62 ? sd - 61 : 0)*9 + (sh >= 62 ? sh - 61 : 0)*3
                  + (sw >= 62 ? sw - 61 : 0);
        }
#pragma unroll
        for (int kk = 0; kk < 8; ++kk)
          if (cnts[kk] != cnts[cg]) sc8[kk] -= 100.f;
      }
      float mx = sc8[0];
#pragma unroll
      for (int kk = 1; kk < 8; ++kk) mx = fmaxf(mx, sc8[kk]);
      float pr[8], lsum = 0.f;
#pragma unroll
      for (int kk = 0; kk < 8; ++kk) { pr[kk] = __expf(sc8[kk] - mx); lsum += pr[kk]; }
      const float inv = __builtin_amdgcn_rcpf(lsum);
      float o[8];
#pragma unroll
      for (int d = 0; d < 8; ++d) o[d] = 0.f;
#pragma unroll
      for (int kk = 0; kk < 8; ++kk) {
        const short8 vv = *(const short8*)&vL[(w*8 + kk)*72 + s8*8];
#pragma unroll
        for (int d = 0; d < 8; ++d) o[d] += pr[kk] * bf2f((u16)vv[d]);
      }
      short8 ov;
#pragma unroll
      for (int d = 0; d < 8; ++d) ov[d] = (short)f2bf(o[d] * inv);
      *(short8*)&qL[tq*72 + s8*8] = ov;    // O into own q-slot
    }
    // prefetch residual x + scatter offsets (x is L3-resident)
    int offs[8]; float xr[8];
#pragma unroll
    for (int mt = 0; mt < 2; ++mt)
#pragma unroll
      for (int r = 0; r < 4; ++r) {
        const int off = scat(wbase, b, mt*16 + quad*4 + r) + w*16 + col;
        offs[mt*4 + r] = off;
        xr[mt*4 + r]   = ld<F32>(x, off);
      }
    __syncthreads();                                       // B3: O ready

    // ---- phase 4: proj MFMA + scattered residual write (y -> out) ----
    {
      f32x4 c0 = (f32x4){0.f,0.f,0.f,0.f}, c1 = (f32x4){0.f,0.f,0.f,0.f};
      c0 = MFMA(*(const short8*)&qL[(col)*72 + quad*8],         bp[0], c0, 0, 0, 0);
      c0 = MFMA(*(const short8*)&qL[(col)*72 + 32 + quad*8],    bp[1], c0, 0, 0, 0);
      c1 = MFMA(*(const short8*)&qL[(16+col)*72 + quad*8],      bp[0], c1, 0, 0, 0);
      c1 = MFMA(*(const short8*)&qL[(16+col)*72 + 32 + quad*8], bp[1], c1, 0, 0, 0);
#pragma unroll
      for (int r = 0; r < 4; ++r) {
        out[offs[r]]     = xr[r]     + c0[r] + pbv;
        out[offs[4 + r]] = xr[4 + r] + c1[r] + pbv;
      }
    }
    __syncthreads();   // B4: fence qL reads vs next chunk's phase-2 writes
  }
}

__global__ __launch_bounds__(256, 4)
void attn_kernel(const void* __restrict__ x,
                 const void* __restrict__ n1g, const void* __restrict__ n1b,
                 const void* __restrict__ qkvw, const void* __restrict__ qkvb,
                 const void* __restrict__ rpb,
                 const void* __restrict__ projw, const void* __restrict__ projb,
                 const int* __restrict__ flag, float* __restrict__ out)
{
  __shared__ __align__(16) u16 aL[32*72];   // 4.6 KB
  __shared__ __align__(16) u16 qL[32*72];   // 4.6 KB (q, then O)
  __shared__ __align__(16) u16 kL[32*72];   // 4.6 KB
  __shared__ __align__(16) u16 vL[32*72];   // 4.6 KB  (18.4 KB total)
  if (*flag)
    attn_body<true >(x, n1g, n1b, qkvw, qkvb, rpb, projw, projb, out, aL, qL, kL, vL);
  else
    attn_body<false>(x, n1g, n1b, qkvw, qkvb, rpb, projw, projb, out, aL, qL, kL, vL);
}

// ---------------------------------------------------------------------------
// Kernel 2: LN2 + MLP(64->256 GELU ->64) + residual, in-place on out (=y).
// Token-major group-reduce LN2; y stashed in LDS (yL) and reused as residual
// (removes the second global read of io per chunk). Cross-chunk prefetch.
// ---------------------------------------------------------------------------
template<bool F32>
__device__ __forceinline__ void mlp_body(
    float* __restrict__ io,
    const void* __restrict__ n2g, const void* __restrict__ n2b,
    const void* __restrict__ mw1, const void* __restrict__ mb1,
    const void* __restrict__ mw2, const void* __restrict__ mb2,
    u16* __restrict__ aL, u16* __restrict__ hL, float* __restrict__ yL)
{
  const int tid  = threadIdx.x;
  const int w    = tid >> 6, l = tid & 63;
  const int quad = l >> 4,  col = l & 15;
  const int s8   = l >> 3,  cg  = l & 7;
  const int ltok = w*8 + s8;

  float g2v[8], be2v[8];
#pragma unroll
  for (int j = 0; j < 8; ++j) {
    g2v[j]  = ld<F32>(n2g, cg*8 + j);
    be2v[j] = ld<F32>(n2b, cg*8 + j);
  }

  short8 b1f[2][4];                  // [kt][nt], W1 cols w*64+nt*16+col
#pragma unroll
  for (int kt = 0; kt < 2; ++kt)
#pragma unroll
    for (int nt = 0; nt < 4; ++nt) {
      short8 f;
#pragma unroll
      for (int j = 0; j < 8; ++j)
        f[j] = (short)f2bf(ld<F32>(mw1, (kt*32 + quad*8 + j)*256 + w*64 + nt*16 + col));
      b1f[kt][nt] = f;
    }
  short8 b2f[8];                     // [kt], W2 col w*16+col
#pragma unroll
  for (int kt = 0; kt < 8; ++kt) {
    short8 f;
#pragma unroll
    for (int j = 0; j < 8; ++j)
      f[j] = (short)f2bf(ld<F32>(mw2, (kt*32 + quad*8 + j)*64 + w*16 + col));
    b2f[kt] = f;
  }
  float b1vv[4];
#pragma unroll
  for (int nt = 0; nt < 4; ++nt) b1vv[nt] = ld<F32>(mb1, w*64 + nt*16 + col);
  const float b2vv = ld<F32>(mb2, w*16 + col);

  float pf[8];
  {
    const float* p = &io[(blockIdx.x*32 + ltok)*64 + cg*8];
    const f32x4 a = *(const f32x4*)p;
    const f32x4 c = *(const f32x4*)(p + 4);
    pf[0]=a[0]; pf[1]=a[1]; pf[2]=a[2]; pf[3]=a[3];
    pf[4]=c[0]; pf[5]=c[1]; pf[6]=c[2]; pf[7]=c[3];
  }

  for (int chunk = blockIdx.x; chunk < 16384; chunk += 2048) {
    // ---- LN2 (token-major group reduce) + stash y in yL ----
    {
      float s1 = 0.f, sq = 0.f;
#pragma unroll
      for (int j = 0; j < 8; ++j) { s1 += pf[j]; sq += pf[j]*pf[j]; }
#pragma unroll
      for (int m = 1; m < 8; m <<= 1) {
        s1 += __shfl_xor(s1, m);
        sq += __shfl_xor(sq, m);
      }
      const float mu  = s1 * 0.015625f;
      const float var = sq * 0.015625f - mu * mu;
      const float rs  = rsqrtf(var + 1e-5f);
      short8 av;
#pragma unroll
      for (int j = 0; j < 8; ++j)
        av[j] = (short)f2bf((pf[j] - mu) * rs * g2v[j] + be2v[j]);
      *(short8*)&aL[ltok*72 + cg*8] = av;
      *(f32x4*)&yL[ltok*68 + cg*8]     = (f32x4){pf[0], pf[1], pf[2], pf[3]};
      *(f32x4*)&yL[ltok*68 + cg*8 + 4] = (f32x4){pf[4], pf[5], pf[6], pf[7]};
    }
    if (chunk + 2048 < 16384) {
      const float* p = &io[((chunk + 2048)*32 + ltok)*64 + cg*8];
      const f32x4 a = *(const f32x4*)p;
      const f32x4 c = *(const f32x4*)(p + 4);
      pf[0]=a[0]; pf[1]=a[1]; pf[2]=a[2]; pf[3]=a[3];
      pf[4]=c[0]; pf[5]=c[1]; pf[6]=c[2]; pf[7]=c[3];
    }
    __syncthreads();                                       // B1: aL/yL ready

    // ---- phase 1: 32x64 @ 64x256 -> wave's 32x64 slab, GELU -> hL ----
    {
      short8 aF[2][2];
#pragma unroll
      for (int mt = 0; mt < 2; ++mt)
#pragma unroll
        for (int kt = 0; kt < 2; ++kt)
          aF[mt][kt] = *(const short8*)&aL[(mt*16 + col)*72 + kt*32 + quad*8];
#pragma unroll
      for (int nt = 0; nt < 4; ++nt) {
        f32x4 m0 = (f32x4){0.f,0.f,0.f,0.f}, m1 = (f32x4){0.f,0.f,0.f,0.f};
        m0 = MFMA(aF[0][0], b1f[0][nt], m0, 0, 0, 0);
        m0 = MFMA(aF[0][1], b1f[1][nt], m0, 0, 0, 0);
        m1 = MFMA(aF[1][0], b1f[0][nt], m1, 0, 0, 0);
        m1 = MFMA(aF[1][1], b1f[1][nt], m1, 0, 0, 0);
        const float bb = b1vv[nt];
#pragma unroll
        for (int r = 0; r < 4; ++r) {
          {
            const float h = m0[r] + bb;
            const float u = h * (1.5957691216f + 0.0713548162f * (h * h));
            const float e = __expf(u);
            hL[(quad*4 + r)*264 + w*64 + nt*16 + col] =
                f2bf(h - h * __builtin_amdgcn_rcpf(e + 1.f));
          }
          {
            const float h = m1[r] + bb;
            const float u = h * (1.5957691216f + 0.0713548162f * (h * h));
            const float e = __expf(u);
            hL[(16 + quad*4 + r)*264 + w*64 + nt*16 + col] =
                f2bf(h - h * __builtin_amdgcn_rcpf(e + 1.f));
          }
        }
      }
    }
    __syncthreads();                                       // B2: hL ready

    // ---- phase 2: 32x256 @ 256x64 + residual from yL -> out ----
    {
      f32x4 o0 = (f32x4){0.f,0.f,0.f,0.f}, o1 = (f32x4){0.f,0.f,0.f,0.f};
#pragma unroll
      for (int kt = 0; kt < 8; ++kt) {
        o0 = MFMA(*(const short8*)&hL[(col)*264 + kt*32 + quad*8],    b2f[kt], o0, 0, 0, 0);
        o1 = MFMA(*(const short8*)&hL[(16+col)*264 + kt*32 + quad*8], b2f[kt], o1, 0, 0, 0);
      }
#pragma unroll
      for (int r = 0; r < 4; ++r) {
        const int r0 = quad*4 + r, r1 = 16 + quad*4 + r;
        io[(chunk*32 + r0)*64 + w*16 + col] = yL[r0*68 + w*16 + col] + o0[r] + b2vv;
        io[(chunk*32 + r1)*64 + w*16 + col] = yL[r1*68 + w*16 + col] + o1[r] + b2vv;
      }
    }
    __syncthreads();   // B3: fence yL/hL reads vs next chunk's writes
  }
}

__global__ __launch_bounds__(256, 4)
void mlp_kernel(float* __restrict__ io,
                const void* __restrict__ n2g, const void* __restrict__ n2b,
                const void* __restrict__ mw1, const void* __restrict__ mb1,
                const void* __restrict__ mw2, const void* __restrict__ mb2,
                const int* __restrict__ flag)
{
  __shared__ __align__(16) u16   aL[32 * 72];    //  4.6 KB
  __shared__ __align__(16) u16   hL[32 * 264];   // 16.9 KB
  __shared__ __align__(16) float yL[32 * 68];    //  8.7 KB  (30.2 KB total)
  if (*flag)
    mlp_body<true >(io, n2g, n2b, mw1, mb1, mw2, mb2, aL, hL, yL);
  else
    mlp_body<false>(io, n2g, n2b, mw1, mb1, mw2, mb2, aL, hL, yL);
}

extern "C" void kernel_launch(void* const* d_in, const int* in_sizes, int n_in,
                              void* d_out, int out_size, void* d_ws, size_t ws_size,
                              hipStream_t stream) {
  const void* x     = d_in[0];
  const void* n1g   = d_in[1];
  const void* n1b   = d_in[2];
  const void* qkvw  = d_in[3];
  const void* qkvb  = d_in[4];
  const void* rpb   = d_in[5];
  const void* projw = d_in[6];
  const void* projb = d_in[7];
  const void* n2g   = d_in[8];
  const void* n2b   = d_in[9];
  const void* mw1   = d_in[10];
  const void* mb1   = d_in[11];
  const void* mw2   = d_in[12];
  const void* mb2   = d_in[13];
  float* out = (float*)d_out;
  int* flag  = (int*)d_ws;

  detect_kernel<<<dim3(1), dim3(64), 0, stream>>>(x, flag);
  attn_kernel<<<dim3(2048), dim3(256), 0, stream>>>(
      x, n1g, n1b, qkvw, qkvb, rpb, projw, projb, flag, out);
  mlp_kernel<<<dim3(2048), dim3(256), 0, stream>>>(
      out, n2g, n2b, mw1, mb1, mw2, mb2, flag);
}